// Round 9
// baseline (2169.029 us; speedup 1.0000x reference)
//
#include <hip/hip_runtime.h>
#include <hip/hip_bf16.h>
#include <math.h>

#define B_ 8
#define L_ 512
#define DV_ 512
#define DM_ 512
#define PL_ 96
#define EL_ 3
#define DS_ 16
#define DC_ 4
#define DI_ 1024
#define DTR_ 32
#define S_ 512
#define CH_ 16         // scan chunks
#define CS_ 32         // steps per chunk

typedef float f32x4 __attribute__((ext_vector_type(4)));
typedef short bf16x8 __attribute__((ext_vector_type(8)));

__device__ __forceinline__ float bf2f(short s) {
  unsigned u = ((unsigned)(unsigned short)s) << 16;
  return __builtin_bit_cast(float, u);
}
__device__ __forceinline__ short f2bf(float f) {
  unsigned u = __builtin_bit_cast(unsigned, f);
  u = u + 0x7FFFu + ((u >> 16) & 1u);   // RNE
  return (short)(u >> 16);
}
__device__ __forceinline__ float h2f(unsigned short u) {
  _Float16 h = __builtin_bit_cast(_Float16, u);
  return (float)h;
}
__device__ __forceinline__ unsigned short f2h(float f) {
  _Float16 h = (_Float16)f;
  return __builtin_bit_cast(unsigned short, h);
}

// lgkm-only barrier (no vmcnt drain) for the dbuf GEMM K-loop.
__device__ __forceinline__ void lds_barrier() {
  __builtin_amdgcn_sched_barrier(0);
  __builtin_amdgcn_s_waitcnt(0xC07F);
  __builtin_amdgcn_s_barrier();
  __builtin_amdgcn_sched_barrier(0);
}

// ---------------------------------------------------------------------------
// fp32 -> bf16 weight conversion, up to 3 segments in one launch.
// ---------------------------------------------------------------------------
__global__ __launch_bounds__(256)
void cvt3_k(short* __restrict__ d1, const float* __restrict__ s1, int n1,
            short* __restrict__ d2, const float* __restrict__ s2, int n2,
            short* __restrict__ d3, const float* __restrict__ s3, int n3)
{
  int total = n1 + n2 + n3;
  for (int i = blockIdx.x * 256 + threadIdx.x; i < total; i += gridDim.x * 256) {
    if (i < n1) d1[i] = f2bf(s1[i]);
    else if (i < n1 + n2) d2[i - n1] = f2bf(s2[i - n1]);
    else d3[i - n1 - n2] = f2bf(s3[i - n1 - n2]);
  }
}

// ---------------------------------------------------------------------------
// Instance-norm statistics over the time axis (L) of x (B,L,DV) fp32.
// ---------------------------------------------------------------------------
__global__ __launch_bounds__(256)
void stats_k(const float* __restrict__ x, float* __restrict__ means,
             float* __restrict__ stdev, float* __restrict__ rstd,
             float* __restrict__ xlast)
{
  int d = blockIdx.x * 256 + threadIdx.x;       // 0..511
  int b = blockIdx.y;
  const float* xp = x + (size_t)b * L_ * DV_ + d;
  float s = 0.f, ss = 0.f;
  for (int l = 0; l < L_; l++) {
    float v = xp[(size_t)l * DV_];
    s += v; ss += v * v;
  }
  float mu = s / (float)L_;
  float var = ss / (float)L_ - mu * mu;
  float sd = sqrtf(var + 1e-5f);
  float rs = 1.f / sd;
  int idx = b * DV_ + d;
  means[idx] = mu; stdev[idx] = sd; rstd[idx] = rs;
  xlast[idx] = (xp[(size_t)(L_ - 1) * DV_] - mu) * rs;
}

// ---------------------------------------------------------------------------
// Normalize + transpose: xnT[b,d,l] = (x[b,l,d]-mu[b,d])*rstd[b,d]  (bf16)
// ---------------------------------------------------------------------------
__global__ __launch_bounds__(256)
void tnorm_k(const float* __restrict__ x, const float* __restrict__ means,
             const float* __restrict__ rstd, short* __restrict__ xnT)
{
  __shared__ float tile[64][65];
  const int t = threadIdx.x;
  const int j = t & 63;
  const int i0 = t >> 6;                 // 0..3
  const int bz = blockIdx.z;
  const int l0 = blockIdx.y << 6;
  const int d0 = blockIdx.x << 6;
  const float* xp = x + ((size_t)bz * L_ + l0) * DV_ + d0;
  #pragma unroll
  for (int i = i0; i < 64; i += 4) tile[i][j] = xp[(size_t)i * DV_ + j];
  __syncthreads();
  short* op = xnT + ((size_t)bz * DV_ + d0) * L_ + l0;
  const int sb = bz * DV_ + d0;
  #pragma unroll
  for (int i = i0; i < 64; i += 4) {
    float mu = means[sb + i];
    float rs = rstd[sb + i];
    op[(size_t)i * L_ + j] = f2bf((tile[j][i] - mu) * rs);
  }
}

// ---------------------------------------------------------------------------
// Fused LayerNorm: optionally h += add (+ abias) in place, then LN -> bf16.
// ADD: 0 = plain, 1 = h += bf16 add, 2 = h += bf16 add + fp32 bias[col].
// ---------------------------------------------------------------------------
template <int ADD>
__global__ __launch_bounds__(256)
void ln_k(float* __restrict__ X, const short* __restrict__ add,
          const float* __restrict__ abias,
          const float* __restrict__ g, const float* __restrict__ b,
          short* __restrict__ Y)
{
  int row = blockIdx.x;
  float* x = X + (size_t)row * DM_;
  int t = threadIdx.x;
  float v0 = x[t], v1 = x[t + 256];
  if constexpr (ADD >= 1) {
    v0 += bf2f(add[(size_t)row * DM_ + t]);
    v1 += bf2f(add[(size_t)row * DM_ + t + 256]);
    if constexpr (ADD == 2) { v0 += abias[t]; v1 += abias[t + 256]; }
    x[t] = v0; x[t + 256] = v1;
  }
  float s = v0 + v1, ss = v0 * v0 + v1 * v1;
  #pragma unroll
  for (int o = 1; o < 64; o <<= 1) { s += __shfl_xor(s, o); ss += __shfl_xor(ss, o); }
  __shared__ float sb[8];
  int wave = t >> 6, lane = t & 63;
  if (lane == 0) { sb[wave] = s; sb[4 + wave] = ss; }
  __syncthreads();
  s = sb[0] + sb[1] + sb[2] + sb[3];
  ss = sb[4] + sb[5] + sb[6] + sb[7];
  float mu = s / (float)DM_;
  float var = ss / (float)DM_ - mu * mu;
  float rs = rsqrtf(var + 1e-5f);
  Y[(size_t)row * DM_ + t]       = f2bf((v0 - mu) * rs * g[t]       + b[t]);
  Y[(size_t)row * DM_ + t + 256] = f2bf((v1 - mu) * rs * g[t + 256] + b[t + 256]);
}

// ---------------------------------------------------------------------------
// Depthwise causal conv (DC=4 taps) + bias + silu.  REV templated.
// ---------------------------------------------------------------------------
template <int REV>
__global__ __launch_bounds__(256)
void conv_k(const short* __restrict__ xz, const float* __restrict__ w,
            const float* __restrict__ cb, short* __restrict__ xc)
{
  int idx = blockIdx.x * 256 + threadIdx.x;   // over B*S*DI
  int i = idx & (DI_ - 1);
  int bs = idx >> 10;                         // b*S + t
  int tt0 = bs & (S_ - 1);
  int b = bs >> 9;
  const short* u = xz + (size_t)b * S_ * (2 * DI_) + i;   // row stride 2*DI
  float acc = cb[i];
  #pragma unroll
  for (int k = 0; k < DC_; k++) {
    int tt = REV ? (tt0 + (DC_ - 1) - k) : (tt0 - (DC_ - 1) + k);
    if (tt >= 0 && tt < S_)
      acc += w[i * DC_ + k] * bf2f(u[(size_t)tt * (2 * DI_)]);
  }
  float sig = 1.f / (1.f + __expf(-acc));
  xc[idx] = f2bf(acc * sig);
}

// ---------------------------------------------------------------------------
// Chunked selective scan, thread owns (b,i,chunk) with all 16 n-states in
// registers.  P1: local scan from 0, store chunk state + prod(dA) (fp16).
// P2: inter-chunk combine.  P3: recompute with incoming state, emit
// y = (sum_n h*C + u*D)*silu(z).   part layout: [((c*B+b)*DI+i)*16+n] fp16
// ---------------------------------------------------------------------------
template <int REV>
__global__ __launch_bounds__(256)
void scan_p1(const unsigned short* __restrict__ dt16, const short* __restrict__ xc,
             const short* __restrict__ xdbl, const float* __restrict__ A_log,
             unsigned short* __restrict__ part_h, unsigned short* __restrict__ part_A)
{
  const int g = blockIdx.x * 256 + threadIdx.x;   // b*DI + i
  const int b = g >> 10, i = g & (DI_ - 1);
  const int c = blockIdx.y;
  float Ai[16];
  const float* al = A_log + i * DS_;
  #pragma unroll
  for (int n = 0; n < 16; n++) Ai[n] = -__expf(al[n]);

  const int ti0 = REV ? (S_ - 1 - c * CS_) : (c * CS_);
  const unsigned short* pdt = dt16 + ((size_t)b * S_ + ti0) * DI_ + i;
  const short* pu = xc + ((size_t)b * S_ + ti0) * DI_ + i;
  const short* pbc = xdbl + (((size_t)b * S_ + ti0) << 6) + DTR_;
  const int sdt = REV ? -DI_ : DI_;
  const int sbc = REV ? -64 : 64;

  float h[16], pA[16];
  #pragma unroll
  for (int n = 0; n < 16; n++) { h[n] = 0.f; pA[n] = 1.f; }

  #pragma unroll 4
  for (int sl = 0; sl < CS_; sl++) {
    float dtv = h2f(*pdt);
    float u = bf2f(*pu);
    bf16x8 vB0 = ((const bf16x8*)pbc)[0];
    bf16x8 vB1 = ((const bf16x8*)pbc)[1];
    float du = dtv * u;
    #pragma unroll
    for (int n = 0; n < 8; n++) {
      float dA = __expf(dtv * Ai[n]);
      h[n] = dA * h[n] + du * bf2f(vB0[n]);
      pA[n] *= dA;
    }
    #pragma unroll
    for (int n = 0; n < 8; n++) {
      float dA = __expf(dtv * Ai[8 + n]);
      h[8 + n] = dA * h[8 + n] + du * bf2f(vB1[n]);
      pA[8 + n] *= dA;
    }
    pdt += sdt; pu += sdt; pbc += sbc;
  }
  unsigned short hv[16], av[16];
  #pragma unroll
  for (int n = 0; n < 16; n++) { hv[n] = f2h(h[n]); av[n] = f2h(pA[n]); }
  const size_t ix = (((size_t)c * B_ + b) * DI_ + i) << 4;
  #pragma unroll
  for (int q = 0; q < 2; q++) {
    ((int4*)(part_h + ix))[q] = ((const int4*)hv)[q];
    ((int4*)(part_A + ix))[q] = ((const int4*)av)[q];
  }
}

__global__ __launch_bounds__(256)
void scan_p2(unsigned short* __restrict__ part_h,
             const unsigned short* __restrict__ part_A)
{
  const size_t gid = (size_t)blockIdx.x * 256 + threadIdx.x;   // B*DI*DS
  const size_t stride = (size_t)B_ * DI_ * DS_;
  float hin = 0.f;
  #pragma unroll
  for (int c = 0; c < CH_; c++) {
    size_t ix = (size_t)c * stride + gid;
    float hh = h2f(part_h[ix]);
    float pA = h2f(part_A[ix]);
    part_h[ix] = f2h(hin);            // becomes chunk c's incoming state
    hin = hh + pA * hin;
  }
}

// NOTE: y may alias dt16 (element-exact same indices; per-element the dt read
// feeds the value stored to y, so dataflow orders them).  No __restrict__ on
// those two.
template <int REV>
__global__ __launch_bounds__(256)
void scan_p3(const unsigned short* dt16, const short* __restrict__ xc,
             const short* __restrict__ xdbl, const short* __restrict__ xz,
             const float* __restrict__ A_log, const float* __restrict__ Dp,
             const unsigned short* __restrict__ part_h, short* y)
{
  const int g = blockIdx.x * 256 + threadIdx.x;   // b*DI + i
  const int b = g >> 10, i = g & (DI_ - 1);
  const int c = blockIdx.y;
  float Ai[16];
  const float* al = A_log + i * DS_;
  #pragma unroll
  for (int n = 0; n < 16; n++) Ai[n] = -__expf(al[n]);
  const float Di = Dp[i];

  float h[16];
  {
    const size_t ix = (((size_t)c * B_ + b) * DI_ + i) << 4;
    unsigned short hv[16];
    ((int4*)hv)[0] = ((const int4*)(part_h + ix))[0];
    ((int4*)hv)[1] = ((const int4*)(part_h + ix))[1];
    #pragma unroll
    for (int n = 0; n < 16; n++) h[n] = h2f(hv[n]);
  }

  const int ti0 = REV ? (S_ - 1 - c * CS_) : (c * CS_);
  const unsigned short* pdt = dt16 + ((size_t)b * S_ + ti0) * DI_ + i;
  const short* pu = xc + ((size_t)b * S_ + ti0) * DI_ + i;
  const short* pbc = xdbl + (((size_t)b * S_ + ti0) << 6) + DTR_;
  const short* pz = xz + ((size_t)b * S_ + ti0) * (2 * DI_) + DI_ + i;
  short* py = y + ((size_t)b * S_ + ti0) * DI_ + i;
  const int sdt = REV ? -DI_ : DI_;
  const int sbc = REV ? -64 : 64;
  const int sz = REV ? -(2 * DI_) : (2 * DI_);

  #pragma unroll 4
  for (int sl = 0; sl < CS_; sl++) {
    float dtv = h2f(*pdt);
    float u = bf2f(*pu);
    bf16x8 vB0 = ((const bf16x8*)pbc)[0];
    bf16x8 vB1 = ((const bf16x8*)pbc)[1];
    bf16x8 vC0 = ((const bf16x8*)pbc)[2];
    bf16x8 vC1 = ((const bf16x8*)pbc)[3];
    float zv = bf2f(*pz);
    float du = dtv * u;
    float yp = 0.f;
    #pragma unroll
    for (int n = 0; n < 8; n++) {
      float dA = __expf(dtv * Ai[n]);
      h[n] = dA * h[n] + du * bf2f(vB0[n]);
      yp += h[n] * bf2f(vC0[n]);
    }
    #pragma unroll
    for (int n = 0; n < 8; n++) {
      float dA = __expf(dtv * Ai[8 + n]);
      h[8 + n] = dA * h[8 + n] + du * bf2f(vB1[n]);
      yp += h[8 + n] * bf2f(vC1[n]);
    }
    float sil = zv / (1.f + __expf(-zv));
    *py = f2bf((yp + u * Di) * sil);
    pdt += sdt; pu += sdt; pbc += sbc; pz += sz; py += sdt;
  }
}

// ---------------------------------------------------------------------------
// bf16 MFMA GEMM: C[M,N] = A[M,K] * W[N,K]^T, fp32 accum.  Both operands
// bf16 (weights pre-converted).  Optional split-source: for K-slabs past
// khalf, A/W load from A1/W1 (base switch is slab-uniform) — used by the
// concat-K out-projection.  Double-buffered LDS + lgkm-only barrier,
// XOR-swizzled LDS, 2x2 waves, m-fastest grid for XCD L2 locality of A.
// All epilogues are pure streaming stores (no RMW).
// ---------------------------------------------------------------------------
enum { EPI_F32_BIAS, EPI_BF16, EPI_F16_SOFTPLUS, EPI_HALF_BF16, EPI_GELU,
       EPI_PROJ };

template <int EPI, int BM, int BN, int BK>
__global__ __launch_bounds__(256)
void gemm_k(const short* __restrict__ A0, const short* __restrict__ A1,
            const short* __restrict__ W0, const short* __restrict__ W1,
            int khalf, int N, int K, int lda, int ldw,
            float* __restrict__ Cf, short* __restrict__ Cb, int ldc,
            const float* __restrict__ bias,
            const float* __restrict__ xlast, const float* __restrict__ stdev,
            const float* __restrict__ means)
{
  constexpr int MT = BM / 32;
  constexpr int NT = BN / 32;
  constexpr int KS = BK / 32;
  constexpr int CHK = BK / 8;
  constexpr int MSK = CHK - 1;
  constexpr int NA = (BM * CHK) / 256;
  constexpr int NW = (BN * CHK) / 256;
  __shared__ __align__(16) short As[2][BM * BK];
  __shared__ __align__(16) short Ws[2][BN * BK];
  const int tid = threadIdx.x;
  const int m0 = blockIdx.x * BM;       // fastest dim = m (XCD locality of A)
  const int n0 = blockIdx.y * BN;
  const int wave = tid >> 6, lane = tid & 63;
  const int wm = (wave & 1) * (BM / 2), wn = (wave >> 1) * (BN / 2);
  const int quad = lane >> 4, l16 = lane & 15;

  f32x4 acc[MT][NT] = {};

  size_t aoff[NA]; int apos[NA];
  #pragma unroll
  for (int j = 0; j < NA; j++) {
    int id = tid + j * 256;
    int r = id / CHK, q = id % CHK;
    aoff[j] = (size_t)(m0 + r) * lda + q * 8;
    apos[j] = r * BK + ((q ^ (r & MSK)) << 3);
  }
  size_t woff[NW]; int wpos[NW];
  #pragma unroll
  for (int j = 0; j < NW; j++) {
    int id = tid + j * 256;
    int r = id / CHK, q = id % CHK;
    int wr = n0 + r; if (wr > N - 1) wr = N - 1;
    woff[j] = (size_t)wr * ldw + q * 8;
    wpos[j] = r * BK + ((q ^ (r & MSK)) << 3);
  }

  const int KB = K / BK;
  int4 avr[NA], wvr[NW];

  // slab 0 (always from A0/W0 since khalf >= BK)
  #pragma unroll
  for (int j = 0; j < NA; j++) avr[j] = *(const int4*)(A0 + aoff[j]);
  #pragma unroll
  for (int j = 0; j < NW; j++) wvr[j] = *(const int4*)(W0 + woff[j]);
  #pragma unroll
  for (int j = 0; j < NA; j++) *(int4*)(&As[0][0] + apos[j]) = avr[j];
  #pragma unroll
  for (int j = 0; j < NW; j++) *(int4*)(&Ws[0][0] + wpos[j]) = wvr[j];
  if (KB > 1) {
    const short* Ab = (BK < khalf) ? A0 + BK : A1 + (BK - khalf);
    const short* Wb = (BK < khalf) ? W0 + BK : W1 + (BK - khalf);
    #pragma unroll
    for (int j = 0; j < NA; j++) avr[j] = *(const int4*)(Ab + aoff[j]);
    #pragma unroll
    for (int j = 0; j < NW; j++) wvr[j] = *(const int4*)(Wb + woff[j]);
  }
  lds_barrier();

  for (int kb = 0; kb < KB; kb++) {
    const int cur = kb & 1;
    bf16x8 af[MT][KS], bfr[NT][KS];
    #pragma unroll
    for (int mt = 0; mt < MT; mt++)
      #pragma unroll
      for (int st = 0; st < KS; st++)
        af[mt][st] = *(const bf16x8*)(&As[cur][0] + (wm + mt * 16 + l16) * BK +
                                      (((st * 4 + quad) ^ (l16 & MSK)) << 3));
    #pragma unroll
    for (int nt = 0; nt < NT; nt++)
      #pragma unroll
      for (int st = 0; st < KS; st++)
        bfr[nt][st] = *(const bf16x8*)(&Ws[cur][0] + (wn + nt * 16 + l16) * BK +
                                       (((st * 4 + quad) ^ (l16 & MSK)) << 3));
    #pragma unroll
    for (int st = 0; st < KS; st++)
      #pragma unroll
      for (int mt = 0; mt < MT; mt++)
        #pragma unroll
        for (int nt = 0; nt < NT; nt++)
          acc[mt][nt] = __builtin_amdgcn_mfma_f32_16x16x32_bf16(
              af[mt][st], bfr[nt][st], acc[mt][nt], 0, 0, 0);
    if (kb + 1 < KB) {
      #pragma unroll
      for (int j = 0; j < NA; j++) *(int4*)(&As[cur ^ 1][0] + apos[j]) = avr[j];
      #pragma unroll
      for (int j = 0; j < NW; j++) *(int4*)(&Ws[cur ^ 1][0] + wpos[j]) = wvr[j];
      if (kb + 2 < KB) {
        const int k0 = (kb + 2) * BK;
        const short* Ab = (k0 < khalf) ? A0 + k0 : A1 + (k0 - khalf);
        const short* Wb = (k0 < khalf) ? W0 + k0 : W1 + (k0 - khalf);
        #pragma unroll
        for (int j = 0; j < NA; j++) avr[j] = *(const int4*)(Ab + aoff[j]);
        #pragma unroll
        for (int j = 0; j < NW; j++) wvr[j] = *(const int4*)(Wb + woff[j]);
      }
    }
    lds_barrier();
  }

  #pragma unroll
  for (int mt = 0; mt < MT; mt++) {
    #pragma unroll
    for (int nt = 0; nt < NT; nt++) {
      int n = n0 + wn + nt * 16 + l16;
      if (n >= N) continue;
      #pragma unroll
      for (int r = 0; r < 4; r++) {
        int m = m0 + wm + mt * 16 + quad * 4 + r;
        float v = acc[mt][nt][r];
        if constexpr (EPI == EPI_F32_BIAS) {
          Cf[(size_t)m * ldc + n] = v + bias[n];
        } else if constexpr (EPI == EPI_BF16) {
          Cb[(size_t)m * ldc + n] = f2bf(v);
        } else if constexpr (EPI == EPI_F16_SOFTPLUS) {
          float tt = v + bias[n];
          float sp = (tt > 20.f) ? tt : log1pf(__expf(tt));
          ((unsigned short*)Cb)[(size_t)m * ldc + n] = f2h(sp);
        } else if constexpr (EPI == EPI_HALF_BF16) {
          Cb[(size_t)m * ldc + n] = f2bf(0.5f * v);
        } else if constexpr (EPI == EPI_GELU) {
          float tt = v + bias[n];
          Cb[(size_t)m * ldc + n] = f2bf(0.5f * tt * (1.f + erff(tt * 0.70710678118f)));
        } else if constexpr (EPI == EPI_PROJ) {
          int bb = m >> 9, d = m & 511;
          float tt = v + bias[n] + xlast[m];
          tt = tt * stdev[m] + means[m];
          Cf[((size_t)bb * PL_ + n) * DV_ + d] = tt;
        }
      }
    }
  }
}

// ---------------------------------------------------------------------------
extern "C" void kernel_launch(void* const* d_in, const int* in_sizes, int n_in,
                              void* d_out, int out_size, void* d_ws, size_t ws_size,
                              hipStream_t stream)
{
  (void)in_sizes; (void)n_in; (void)out_size; (void)ws_size;
  const float* x        = (const float*)d_in[0];
  const float* emb_w    = (const float*)d_in[1];
  const float* emb_b    = (const float*)d_in[2];
  const float* ln_g     = (const float*)d_in[3];
  const float* ln_b     = (const float*)d_in[4];
  const float* m_in_w   = (const float*)d_in[5];
  const float* m_conv_w = (const float*)d_in[6];
  const float* m_conv_b = (const float*)d_in[7];
  const float* m_xp_w   = (const float*)d_in[8];
  const float* m_dt_w   = (const float*)d_in[9];
  const float* m_dt_b   = (const float*)d_in[10];
  const float* m_A_log  = (const float*)d_in[11];
  const float* m_D      = (const float*)d_in[12];
  const float* m_out_w  = (const float*)d_in[13];
  const float* ffn_ln_g = (const float*)d_in[14];
  const float* ffn_ln_b = (const float*)d_in[15];
  const float* ffn_w1   = (const float*)d_in[16];
  const float* ffn_b1   = (const float*)d_in[17];
  const float* ffn_w2   = (const float*)d_in[18];
  const float* ffn_b2   = (const float*)d_in[19];
  const float* enc_g    = (const float*)d_in[20];
  const float* enc_b    = (const float*)d_in[21];
  const float* proj_w   = (const float*)d_in[22];
  const float* proj_b   = (const float*)d_in[23];
  float* out = (float*)d_out;

  char* ws = (char*)d_ws;
  const size_t MB = 1024 * 1024;
  // ---- workspace map (61 MB + 64 KB, disjoint lifetimes annotated) ----
  float* h      = (float*)(ws + 0);        //  8 MB fp32 residual stream
  short* hn     = (short*)(ws + 8 * MB);   //  4 MB LN output bf16
  short* xz     = (short*)(ws + 12 * MB);  // 16 MB [M][2048] per-dir reuse
  short* xc     = (short*)(ws + 28 * MB);  //  8 MB [M][1024] per-dir reuse
  short* xdbl   = (short*)(ws + 36 * MB);  // .5 MB [M][64]
  float* stats  = (float*)(ws + 36 * MB + 512 * 1024);          // 64 KB
  short* wxp    = (short*)(ws + 36 * MB + 768 * 1024);          // 128 KB bf16 xp_w
  short* wdt    = (short*)(ws + 36 * MB + 896 * 1024);          // 64 KB bf16 dt_w
  unsigned short* dtb = (unsigned short*)(ws + 37 * MB); // 8 MB fp16 dt; p3-d1 writes y in place
  unsigned short* part_h = (unsigned short*)(ws + 45 * MB);     // 4 MB (scan only)
  unsigned short* part_A = (unsigned short*)(ws + 49 * MB);     // 4 MB (scan only)
  short* yact0  = (short*)(ws + 53 * MB);  //  8 MB y(dir0); xnT aliases pre-layer
  short* xnT    = (short*)(ws + 53 * MB);
  // scratch window A (45-47 MB): weights bf16, sequential users
  short* wbig   = (short*)(ws + 45 * MB);  // in_w / out_w-pair / ffn_w1 / ffn_w2 / emb_w / proj_w
  // scratch window B (47-51 MB): vtmp / ftmp bf16 [M][512]
  short* vtmp   = (short*)(ws + 47 * MB);
  short* ftmp   = (short*)(ws + 47 * MB);
  float* means = stats, *stdevp = stats + 4096, *rstd = stats + 8192, *xlast = stats + 12288;

  dim3 blk(256);
  const dim3 cg(1024);

  stats_k<<<dim3(2, B_), blk, 0, stream>>>(x, means, stdevp, rstd, xlast);
  tnorm_k<<<dim3(8, 8, B_), blk, 0, stream>>>(x, means, rstd, xnT);
  cvt3_k<<<cg, blk, 0, stream>>>(wbig, emb_w, DM_ * L_, nullptr, nullptr, 0, nullptr, nullptr, 0);
  gemm_k<EPI_F32_BIAS, 64, 64, 64><<<dim3(64, 8), blk, 0, stream>>>(
      xnT, xnT, wbig, wbig, 1 << 30, DM_, L_, L_, L_,
      h, nullptr, DM_, emb_b, nullptr, nullptr, nullptr);

  for (int il = 0; il < EL_; il++) {
    if (il == 0)
      ln_k<0><<<dim3(4096), blk, 0, stream>>>(h, nullptr, nullptr,
          ln_g, ln_b, hn);
    else
      ln_k<2><<<dim3(4096), blk, 0, stream>>>(h, ftmp, ffn_b2 + (il - 1) * DM_,
          ln_g + il * DM_, ln_b + il * DM_, hn);
    for (int dir = 0; dir < 2; dir++) {
      int mod = 2 * il + dir;
      cvt3_k<<<cg, blk, 0, stream>>>(
          wbig, m_in_w + (size_t)mod * 2 * DI_ * DM_, 2 * DI_ * DM_,
          wxp, m_xp_w + (size_t)mod * (DTR_ + 2 * DS_) * DI_, (DTR_ + 2 * DS_) * DI_,
          wdt, m_dt_w + (size_t)mod * DI_ * DTR_, DI_ * DTR_);
      gemm_k<EPI_BF16, 64, 64, 64><<<dim3(64, 32), blk, 0, stream>>>(
          hn, hn, wbig, wbig, 1 << 30, 2 * DI_, DM_, DM_, DM_,
          nullptr, xz, 2 * DI_, nullptr, nullptr, nullptr, nullptr);
      if (dir == 0)
        conv_k<0><<<dim3(16384), blk, 0, stream>>>(
            xz, m_conv_w + (size_t)mod * DI_ * DC_, m_conv_b + (size_t)mod * DI_, xc);
      else
        conv_k<1><<<dim3(16384), blk, 0, stream>>>(
            xz, m_conv_w + (size_t)mod * DI_ * DC_, m_conv_b + (size_t)mod * DI_, xc);
      gemm_k<EPI_BF16, 64, 64, 64><<<dim3(64, 1), blk, 0, stream>>>(
          xc, xc, wxp, wxp, 1 << 30, DTR_ + 2 * DS_, DI_, DI_, DI_,
          nullptr, xdbl, DTR_ + 2 * DS_, nullptr, nullptr, nullptr, nullptr);
      gemm_k<EPI_F16_SOFTPLUS, 64, 64, 32><<<dim3(64, 16), blk, 0, stream>>>(
          xdbl, xdbl, wdt, wdt, 1 << 30, DI_, DTR_, DTR_ + 2 * DS_, DTR_,
          nullptr, (short*)dtb, DI_, m_dt_b + (size_t)mod * DI_, nullptr, nullptr, nullptr);
      const float* Alog = m_A_log + (size_t)mod * DI_ * DS_;
      const float* Dp = m_D + (size_t)mod * DI_;
      short* ydst = (dir == 0) ? yact0 : (short*)dtb;   // dir1: in-place over dtb
      if (dir == 0) {
        scan_p1<0><<<dim3(32, CH_), blk, 0, stream>>>(dtb, xc, xdbl, Alog, part_h, part_A);
        scan_p2<<<dim3(512), blk, 0, stream>>>(part_h, part_A);
        scan_p3<0><<<dim3(32, CH_), blk, 0, stream>>>(dtb, xc, xdbl, xz, Alog, Dp, part_h, ydst);
      } else {
        scan_p1<1><<<dim3(32, CH_), blk, 0, stream>>>(dtb, xc, xdbl, Alog, part_h, part_A);
        scan_p2<<<dim3(512), blk, 0, stream>>>(part_h, part_A);
        scan_p3<1><<<dim3(32, CH_), blk, 0, stream>>>(dtb, xc, xdbl, xz, Alog, Dp, part_h, ydst);
      }
    }
    // out-proj (concat-K over both directions): vtmp = 0.5*(yf.Wf^T + yb.Wb^T)
    cvt3_k<<<cg, blk, 0, stream>>>(
        wbig, m_out_w + (size_t)(2 * il) * DM_ * DI_, 2 * DM_ * DI_,
        nullptr, nullptr, 0, nullptr, nullptr, 0);
    gemm_k<EPI_HALF_BF16, 64, 64, 64><<<dim3(64, 8), blk, 0, stream>>>(
        yact0, (const short*)dtb, wbig, wbig + (size_t)DM_ * DI_,
        DI_, DM_, 2 * DI_, DI_, DI_,
        nullptr, vtmp, DM_, nullptr, nullptr, nullptr, nullptr);
    // fused: h += vtmp, then LN
    ln_k<1><<<dim3(4096), blk, 0, stream>>>(h, vtmp, nullptr,
        ffn_ln_g + il * DM_, ffn_ln_b + il * DM_, hn);
    cvt3_k<<<cg, blk, 0, stream>>>(
        wbig, ffn_w1 + (size_t)il * 4 * DM_ * DM_, 4 * DM_ * DM_,
        nullptr, nullptr, 0, nullptr, nullptr, 0);
    gemm_k<EPI_GELU, 64, 64, 64><<<dim3(64, 32), blk, 0, stream>>>(
        hn, hn, wbig, wbig, 1 << 30, 4 * DM_, DM_, DM_, DM_,
        nullptr, xz, 4 * DM_, ffn_b1 + (size_t)il * 4 * DM_, nullptr, nullptr, nullptr);
    cvt3_k<<<cg, blk, 0, stream>>>(
        wbig, ffn_w2 + (size_t)il * DM_ * 4 * DM_, DM_ * 4 * DM_,
        nullptr, nullptr, 0, nullptr, nullptr, 0);
    gemm_k<EPI_BF16, 64, 64, 64><<<dim3(64, 8), blk, 0, stream>>>(
        xz, xz, wbig, wbig, 1 << 30, DM_, 4 * DM_, 4 * DM_, 4 * DM_,
        nullptr, ftmp, DM_, nullptr, nullptr, nullptr, nullptr);
    // h += ftmp + ffn_b2 happens in the next layer's LN (or enc-LN below)
  }

  ln_k<2><<<dim3(4096), blk, 0, stream>>>(h, ftmp, ffn_b2 + 2 * DM_,
      enc_g, enc_b, hn);
  cvt3_k<<<cg, blk, 0, stream>>>(wbig, proj_w, PL_ * DM_,
      nullptr, nullptr, 0, nullptr, nullptr, 0);
  gemm_k<EPI_PROJ, 64, 64, 64><<<dim3(64, 2), blk, 0, stream>>>(
      hn, hn, wbig, wbig, 1 << 30, PL_, DM_, DM_, DM_,
      out, nullptr, 0, proj_b, xlast, stdevp, means);
}

// Round 10
// 1590.462 us; speedup vs baseline: 1.3638x; 1.3638x over previous
//
#include <hip/hip_runtime.h>
#include <hip/hip_bf16.h>
#include <math.h>

#define B_ 8
#define L_ 512
#define DV_ 512
#define DM_ 512
#define PL_ 96
#define EL_ 3
#define DS_ 16
#define DC_ 4
#define DI_ 1024
#define DTR_ 32
#define S_ 512
#define CH_ 16         // scan chunks
#define CS_ 32         // steps per chunk

typedef float f32x4 __attribute__((ext_vector_type(4)));
typedef short bf16x8 __attribute__((ext_vector_type(8)));

__device__ __forceinline__ float bf2f(short s) {
  unsigned u = ((unsigned)(unsigned short)s) << 16;
  return __builtin_bit_cast(float, u);
}
__device__ __forceinline__ short f2bf(float f) {
  unsigned u = __builtin_bit_cast(unsigned, f);
  u = u + 0x7FFFu + ((u >> 16) & 1u);   // RNE
  return (short)(u >> 16);
}
__device__ __forceinline__ float h2f(unsigned short u) {
  _Float16 h = __builtin_bit_cast(_Float16, u);
  return (float)h;
}
__device__ __forceinline__ unsigned short f2h(float f) {
  _Float16 h = (_Float16)f;
  return __builtin_bit_cast(unsigned short, h);
}

// lgkm-only barrier (no vmcnt drain): global prefetch stays in flight.
__device__ __forceinline__ void lds_barrier() {
  __builtin_amdgcn_sched_barrier(0);
  __builtin_amdgcn_s_waitcnt(0xC07F);
  __builtin_amdgcn_s_barrier();
  __builtin_amdgcn_sched_barrier(0);
}

__device__ __forceinline__ bf16x8 cvt8(float4 a, float4 b) {
  union { bf16x8 v; __hip_bfloat162 h[4]; } u;
  u.h[0] = __float22bfloat162_rn(float2{a.x, a.y});
  u.h[1] = __float22bfloat162_rn(float2{a.z, a.w});
  u.h[2] = __float22bfloat162_rn(float2{b.x, b.y});
  u.h[3] = __float22bfloat162_rn(float2{b.z, b.w});
  return u.v;
}

// ---------------------------------------------------------------------------
// Instance-norm statistics over the time axis (L) of x (B,L,DV) fp32.
// ---------------------------------------------------------------------------
__global__ __launch_bounds__(256)
void stats_k(const float* __restrict__ x, float* __restrict__ means,
             float* __restrict__ stdev, float* __restrict__ rstd,
             float* __restrict__ xlast)
{
  int d = blockIdx.x * 256 + threadIdx.x;       // 0..511
  int b = blockIdx.y;
  const float* xp = x + (size_t)b * L_ * DV_ + d;
  float s = 0.f, ss = 0.f;
  for (int l = 0; l < L_; l++) {
    float v = xp[(size_t)l * DV_];
    s += v; ss += v * v;
  }
  float mu = s / (float)L_;
  float var = ss / (float)L_ - mu * mu;
  float sd = sqrtf(var + 1e-5f);
  float rs = 1.f / sd;
  int idx = b * DV_ + d;
  means[idx] = mu; stdev[idx] = sd; rstd[idx] = rs;
  xlast[idx] = (xp[(size_t)(L_ - 1) * DV_] - mu) * rs;
}

// ---------------------------------------------------------------------------
// Normalize + transpose: xnT[b,d,l] = (x[b,l,d]-mu[b,d])*rstd[b,d]  (bf16)
// ---------------------------------------------------------------------------
__global__ __launch_bounds__(256)
void tnorm_k(const float* __restrict__ x, const float* __restrict__ means,
             const float* __restrict__ rstd, short* __restrict__ xnT)
{
  __shared__ float tile[64][65];
  const int t = threadIdx.x;
  const int j = t & 63;
  const int i0 = t >> 6;                 // 0..3
  const int bz = blockIdx.z;
  const int l0 = blockIdx.y << 6;
  const int d0 = blockIdx.x << 6;
  const float* xp = x + ((size_t)bz * L_ + l0) * DV_ + d0;
  #pragma unroll
  for (int i = i0; i < 64; i += 4) tile[i][j] = xp[(size_t)i * DV_ + j];
  __syncthreads();
  short* op = xnT + ((size_t)bz * DV_ + d0) * L_ + l0;
  const int sb = bz * DV_ + d0;
  #pragma unroll
  for (int i = i0; i < 64; i += 4) {
    float mu = means[sb + i];
    float rs = rstd[sb + i];
    op[(size_t)i * L_ + j] = f2bf((tile[j][i] - mu) * rs);
  }
}

// ---------------------------------------------------------------------------
// Fused LayerNorm: optionally h += add (+ abias) in place, then LN -> bf16.
// ADD: 0 = plain, 1 = h += bf16 add, 2 = h += bf16 add + fp32 bias[col].
// ---------------------------------------------------------------------------
template <int ADD>
__global__ __launch_bounds__(256)
void ln_k(float* __restrict__ X, const short* __restrict__ add,
          const float* __restrict__ abias,
          const float* __restrict__ g, const float* __restrict__ b,
          short* __restrict__ Y)
{
  int row = blockIdx.x;
  float* x = X + (size_t)row * DM_;
  int t = threadIdx.x;
  float v0 = x[t], v1 = x[t + 256];
  if constexpr (ADD >= 1) {
    v0 += bf2f(add[(size_t)row * DM_ + t]);
    v1 += bf2f(add[(size_t)row * DM_ + t + 256]);
    if constexpr (ADD == 2) { v0 += abias[t]; v1 += abias[t + 256]; }
    x[t] = v0; x[t + 256] = v1;
  }
  float s = v0 + v1, ss = v0 * v0 + v1 * v1;
  #pragma unroll
  for (int o = 1; o < 64; o <<= 1) { s += __shfl_xor(s, o); ss += __shfl_xor(ss, o); }
  __shared__ float sb[8];
  int wave = t >> 6, lane = t & 63;
  if (lane == 0) { sb[wave] = s; sb[4 + wave] = ss; }
  __syncthreads();
  s = sb[0] + sb[1] + sb[2] + sb[3];
  ss = sb[4] + sb[5] + sb[6] + sb[7];
  float mu = s / (float)DM_;
  float var = ss / (float)DM_ - mu * mu;
  float rs = rsqrtf(var + 1e-5f);
  Y[(size_t)row * DM_ + t]       = f2bf((v0 - mu) * rs * g[t]       + b[t]);
  Y[(size_t)row * DM_ + t + 256] = f2bf((v1 - mu) * rs * g[t + 256] + b[t + 256]);
}

// ---------------------------------------------------------------------------
// Depthwise causal conv (DC=4 taps) + bias + silu.  REV templated.
// ---------------------------------------------------------------------------
template <int REV>
__global__ __launch_bounds__(256)
void conv_k(const short* __restrict__ xz, const float* __restrict__ w,
            const float* __restrict__ cb, short* __restrict__ xc)
{
  int idx = blockIdx.x * 256 + threadIdx.x;   // over B*S*DI
  int i = idx & (DI_ - 1);
  int bs = idx >> 10;                         // b*S + t
  int tt0 = bs & (S_ - 1);
  int b = bs >> 9;
  const short* u = xz + (size_t)b * S_ * (2 * DI_) + i;   // row stride 2*DI
  float acc = cb[i];
  #pragma unroll
  for (int k = 0; k < DC_; k++) {
    int tt = REV ? (tt0 + (DC_ - 1) - k) : (tt0 - (DC_ - 1) + k);
    if (tt >= 0 && tt < S_)
      acc += w[i * DC_ + k] * bf2f(u[(size_t)tt * (2 * DI_)]);
  }
  float sig = 1.f / (1.f + __expf(-acc));
  xc[idx] = f2bf(acc * sig);
}

// ---------------------------------------------------------------------------
// Chunked selective scan (validated in rounds 4-9).
// ---------------------------------------------------------------------------
template <int REV>
__global__ __launch_bounds__(256)
void scan_p1(const unsigned short* __restrict__ dt16, const short* __restrict__ xc,
             const short* __restrict__ xdbl, const float* __restrict__ A_log,
             unsigned short* __restrict__ part_h, unsigned short* __restrict__ part_A)
{
  const int g = blockIdx.x * 256 + threadIdx.x;   // b*DI + i
  const int b = g >> 10, i = g & (DI_ - 1);
  const int c = blockIdx.y;
  float Ai[16];
  const float* al = A_log + i * DS_;
  #pragma unroll
  for (int n = 0; n < 16; n++) Ai[n] = -__expf(al[n]);

  const int ti0 = REV ? (S_ - 1 - c * CS_) : (c * CS_);
  const unsigned short* pdt = dt16 + ((size_t)b * S_ + ti0) * DI_ + i;
  const short* pu = xc + ((size_t)b * S_ + ti0) * DI_ + i;
  const short* pbc = xdbl + (((size_t)b * S_ + ti0) << 6) + DTR_;
  const int sdt = REV ? -DI_ : DI_;
  const int sbc = REV ? -64 : 64;

  float h[16], pA[16];
  #pragma unroll
  for (int n = 0; n < 16; n++) { h[n] = 0.f; pA[n] = 1.f; }

  #pragma unroll 4
  for (int sl = 0; sl < CS_; sl++) {
    float dtv = h2f(*pdt);
    float u = bf2f(*pu);
    bf16x8 vB0 = ((const bf16x8*)pbc)[0];
    bf16x8 vB1 = ((const bf16x8*)pbc)[1];
    float du = dtv * u;
    #pragma unroll
    for (int n = 0; n < 8; n++) {
      float dA = __expf(dtv * Ai[n]);
      h[n] = dA * h[n] + du * bf2f(vB0[n]);
      pA[n] *= dA;
    }
    #pragma unroll
    for (int n = 0; n < 8; n++) {
      float dA = __expf(dtv * Ai[8 + n]);
      h[8 + n] = dA * h[8 + n] + du * bf2f(vB1[n]);
      pA[8 + n] *= dA;
    }
    pdt += sdt; pu += sdt; pbc += sbc;
  }
  unsigned short hv[16], av[16];
  #pragma unroll
  for (int n = 0; n < 16; n++) { hv[n] = f2h(h[n]); av[n] = f2h(pA[n]); }
  const size_t ix = (((size_t)c * B_ + b) * DI_ + i) << 4;
  #pragma unroll
  for (int q = 0; q < 2; q++) {
    ((int4*)(part_h + ix))[q] = ((const int4*)hv)[q];
    ((int4*)(part_A + ix))[q] = ((const int4*)av)[q];
  }
}

__global__ __launch_bounds__(256)
void scan_p2(unsigned short* __restrict__ part_h,
             const unsigned short* __restrict__ part_A)
{
  const size_t gid = (size_t)blockIdx.x * 256 + threadIdx.x;   // B*DI*DS
  const size_t stride = (size_t)B_ * DI_ * DS_;
  float hin = 0.f;
  #pragma unroll
  for (int c = 0; c < CH_; c++) {
    size_t ix = (size_t)c * stride + gid;
    float hh = h2f(part_h[ix]);
    float pA = h2f(part_A[ix]);
    part_h[ix] = f2h(hin);            // becomes chunk c's incoming state
    hin = hh + pA * hin;
  }
}

// y may alias dt16 (element-exact same indices) — no __restrict__ on those.
template <int REV>
__global__ __launch_bounds__(256)
void scan_p3(const unsigned short* dt16, const short* __restrict__ xc,
             const short* __restrict__ xdbl, const short* __restrict__ xz,
             const float* __restrict__ A_log, const float* __restrict__ Dp,
             const unsigned short* __restrict__ part_h, short* y)
{
  const int g = blockIdx.x * 256 + threadIdx.x;   // b*DI + i
  const int b = g >> 10, i = g & (DI_ - 1);
  const int c = blockIdx.y;
  float Ai[16];
  const float* al = A_log + i * DS_;
  #pragma unroll
  for (int n = 0; n < 16; n++) Ai[n] = -__expf(al[n]);
  const float Di = Dp[i];

  float h[16];
  {
    const size_t ix = (((size_t)c * B_ + b) * DI_ + i) << 4;
    unsigned short hv[16];
    ((int4*)hv)[0] = ((const int4*)(part_h + ix))[0];
    ((int4*)hv)[1] = ((const int4*)(part_h + ix))[1];
    #pragma unroll
    for (int n = 0; n < 16; n++) h[n] = h2f(hv[n]);
  }

  const int ti0 = REV ? (S_ - 1 - c * CS_) : (c * CS_);
  const unsigned short* pdt = dt16 + ((size_t)b * S_ + ti0) * DI_ + i;
  const short* pu = xc + ((size_t)b * S_ + ti0) * DI_ + i;
  const short* pbc = xdbl + (((size_t)b * S_ + ti0) << 6) + DTR_;
  const short* pz = xz + ((size_t)b * S_ + ti0) * (2 * DI_) + DI_ + i;
  short* py = y + ((size_t)b * S_ + ti0) * DI_ + i;
  const int sdt = REV ? -DI_ : DI_;
  const int sbc = REV ? -64 : 64;
  const int sz = REV ? -(2 * DI_) : (2 * DI_);

  #pragma unroll 4
  for (int sl = 0; sl < CS_; sl++) {
    float dtv = h2f(*pdt);
    float u = bf2f(*pu);
    bf16x8 vB0 = ((const bf16x8*)pbc)[0];
    bf16x8 vB1 = ((const bf16x8*)pbc)[1];
    bf16x8 vC0 = ((const bf16x8*)pbc)[2];
    bf16x8 vC1 = ((const bf16x8*)pbc)[3];
    float zv = bf2f(*pz);
    float du = dtv * u;
    float yp = 0.f;
    #pragma unroll
    for (int n = 0; n < 8; n++) {
      float dA = __expf(dtv * Ai[n]);
      h[n] = dA * h[n] + du * bf2f(vB0[n]);
      yp += h[n] * bf2f(vC0[n]);
    }
    #pragma unroll
    for (int n = 0; n < 8; n++) {
      float dA = __expf(dtv * Ai[8 + n]);
      h[8 + n] = dA * h[8 + n] + du * bf2f(vB1[n]);
      yp += h[8 + n] * bf2f(vC1[n]);
    }
    float sil = zv / (1.f + __expf(-zv));
    *py = f2bf((yp + u * Di) * sil);
    pdt += sdt; pu += sdt; pbc += sbc; pz += sz; py += sdt;
  }
}

// ---------------------------------------------------------------------------
// bf16 MFMA GEMM: C[M,N] = A[M,K] * W[N,K]^T, fp32 accum.  A bf16; W fp32
// converted to bf16 during LDS staging.  Split-source concat-K: slabs past
// khalf read A1/W1 (slab-uniform switch).  Double-buffered LDS + lgkm-only
// barrier + XOR swizzle (validated: conflicts=0).  2x2 waves; m-fastest grid
// for XCD L2 locality of A.  All epilogues streaming (no RMW).
// ---------------------------------------------------------------------------
enum { EPI_F32_BIAS, EPI_BF16, EPI_F16_SOFTPLUS, EPI_HALF_BF16, EPI_GELU,
       EPI_PROJ };

template <int EPI, int BM, int BN, int BK>
__global__ __launch_bounds__(256)
void gemm_k(const short* __restrict__ A0, const short* __restrict__ A1,
            const float* __restrict__ W0, const float* __restrict__ W1,
            int khalf, int N, int K, int lda, int ldw,
            float* __restrict__ Cf, short* __restrict__ Cb, int ldc,
            const float* __restrict__ bias,
            const float* __restrict__ xlast, const float* __restrict__ stdev,
            const float* __restrict__ means)
{
  constexpr int MT = BM / 32;           // 16-row m-tiles per wave
  constexpr int NT = BN / 32;
  constexpr int KS = BK / 32;
  constexpr int CHK = BK / 8;           // 16B chunks per row
  constexpr int MSK = CHK - 1;
  constexpr int NA = (BM * CHK) / 256;
  constexpr int NW = (BN * CHK) / 256;
  __shared__ __align__(16) short As[2][BM * BK];
  __shared__ __align__(16) short Ws[2][BN * BK];
  const int tid = threadIdx.x;
  const int m0 = blockIdx.x * BM;       // fastest dim = m (XCD locality of A)
  const int n0 = blockIdx.y * BN;
  const int wave = tid >> 6, lane = tid & 63;
  const int wm = (wave & 1) * (BM / 2), wn = (wave >> 1) * (BN / 2);
  const int quad = lane >> 4, l16 = lane & 15;

  f32x4 acc[MT][NT] = {};

  size_t aoff[NA]; int apos[NA];
  #pragma unroll
  for (int j = 0; j < NA; j++) {
    int id = tid + j * 256;
    int r = id / CHK, q = id % CHK;
    aoff[j] = (size_t)(m0 + r) * lda + q * 8;
    apos[j] = r * BK + ((q ^ (r & MSK)) << 3);
  }
  size_t woff[NW]; int wpos[NW];
  #pragma unroll
  for (int j = 0; j < NW; j++) {
    int id = tid + j * 256;
    int r = id / CHK, q = id % CHK;
    int wr = n0 + r; if (wr > N - 1) wr = N - 1;
    woff[j] = (size_t)wr * ldw + q * 8;
    wpos[j] = r * BK + ((q ^ (r & MSK)) << 3);
  }

  const int KB = K / BK;
  int4 avr[NA];
  float4 wv0[NW], wv1[NW];

  // prologue: slab 0 -> LDS[0]; issue slab 1 loads (slab-uniform source)
  #pragma unroll
  for (int j = 0; j < NA; j++) avr[j] = *(const int4*)(A0 + aoff[j]);
  #pragma unroll
  for (int j = 0; j < NW; j++) {
    wv0[j] = *(const float4*)(W0 + woff[j]);
    wv1[j] = *(const float4*)(W0 + woff[j] + 4);
  }
  #pragma unroll
  for (int j = 0; j < NA; j++) *(int4*)(&As[0][0] + apos[j]) = avr[j];
  #pragma unroll
  for (int j = 0; j < NW; j++) *(bf16x8*)(&Ws[0][0] + wpos[j]) = cvt8(wv0[j], wv1[j]);
  if (KB > 1) {
    const short* Ab = (BK < khalf) ? A0 + BK : A1 + (BK - khalf);
    const float* Wb = (BK < khalf) ? W0 + BK : W1 + (BK - khalf);
    #pragma unroll
    for (int j = 0; j < NA; j++) avr[j] = *(const int4*)(Ab + aoff[j]);
    #pragma unroll
    for (int j = 0; j < NW; j++) {
      wv0[j] = *(const float4*)(Wb + woff[j]);
      wv1[j] = *(const float4*)(Wb + woff[j] + 4);
    }
  }
  lds_barrier();

  for (int kb = 0; kb < KB; kb++) {
    const int cur = kb & 1;
    bf16x8 af[MT][KS], bfr[NT][KS];
    #pragma unroll
    for (int mt = 0; mt < MT; mt++)
      #pragma unroll
      for (int st = 0; st < KS; st++)
        af[mt][st] = *(const bf16x8*)(&As[cur][0] + (wm + mt * 16 + l16) * BK +
                                      (((st * 4 + quad) ^ (l16 & MSK)) << 3));
    #pragma unroll
    for (int nt = 0; nt < NT; nt++)
      #pragma unroll
      for (int st = 0; st < KS; st++)
        bfr[nt][st] = *(const bf16x8*)(&Ws[cur][0] + (wn + nt * 16 + l16) * BK +
                                       (((st * 4 + quad) ^ (l16 & MSK)) << 3));
    #pragma unroll
    for (int st = 0; st < KS; st++)
      #pragma unroll
      for (int mt = 0; mt < MT; mt++)
        #pragma unroll
        for (int nt = 0; nt < NT; nt++)
          acc[mt][nt] = __builtin_amdgcn_mfma_f32_16x16x32_bf16(
              af[mt][st], bfr[nt][st], acc[mt][nt], 0, 0, 0);
    if (kb + 1 < KB) {
      #pragma unroll
      for (int j = 0; j < NA; j++) *(int4*)(&As[cur ^ 1][0] + apos[j]) = avr[j];
      #pragma unroll
      for (int j = 0; j < NW; j++)
        *(bf16x8*)(&Ws[cur ^ 1][0] + wpos[j]) = cvt8(wv0[j], wv1[j]);
      if (kb + 2 < KB) {
        const int k0 = (kb + 2) * BK;
        const short* Ab = (k0 < khalf) ? A0 + k0 : A1 + (k0 - khalf);
        const float* Wb = (k0 < khalf) ? W0 + k0 : W1 + (k0 - khalf);
        #pragma unroll
        for (int j = 0; j < NA; j++) avr[j] = *(const int4*)(Ab + aoff[j]);
        #pragma unroll
        for (int j = 0; j < NW; j++) {
          wv0[j] = *(const float4*)(Wb + woff[j]);
          wv1[j] = *(const float4*)(Wb + woff[j] + 4);
        }
      }
    }
    lds_barrier();
  }

  #pragma unroll
  for (int mt = 0; mt < MT; mt++) {
    #pragma unroll
    for (int nt = 0; nt < NT; nt++) {
      int n = n0 + wn + nt * 16 + l16;
      if (n >= N) continue;
      #pragma unroll
      for (int r = 0; r < 4; r++) {
        int m = m0 + wm + mt * 16 + quad * 4 + r;
        float v = acc[mt][nt][r];
        if constexpr (EPI == EPI_F32_BIAS) {
          Cf[(size_t)m * ldc + n] = v + bias[n];
        } else if constexpr (EPI == EPI_BF16) {
          Cb[(size_t)m * ldc + n] = f2bf(v);
        } else if constexpr (EPI == EPI_F16_SOFTPLUS) {
          float tt = v + bias[n];
          float sp = (tt > 20.f) ? tt : log1pf(__expf(tt));
          ((unsigned short*)Cb)[(size_t)m * ldc + n] = f2h(sp);
        } else if constexpr (EPI == EPI_HALF_BF16) {
          Cb[(size_t)m * ldc + n] = f2bf(0.5f * v);
        } else if constexpr (EPI == EPI_GELU) {
          float tt = v + bias[n];
          Cb[(size_t)m * ldc + n] = f2bf(0.5f * tt * (1.f + erff(tt * 0.70710678118f)));
        } else if constexpr (EPI == EPI_PROJ) {
          int bb = m >> 9, d = m & 511;
          float tt = v + bias[n] + xlast[m];
          tt = tt * stdev[m] + means[m];
          Cf[((size_t)bb * PL_ + n) * DV_ + d] = tt;
        }
      }
    }
  }
}

// ---------------------------------------------------------------------------
extern "C" void kernel_launch(void* const* d_in, const int* in_sizes, int n_in,
                              void* d_out, int out_size, void* d_ws, size_t ws_size,
                              hipStream_t stream)
{
  (void)in_sizes; (void)n_in; (void)out_size; (void)ws_size;
  const float* x        = (const float*)d_in[0];
  const float* emb_w    = (const float*)d_in[1];
  const float* emb_b    = (const float*)d_in[2];
  const float* ln_g     = (const float*)d_in[3];
  const float* ln_b     = (const float*)d_in[4];
  const float* m_in_w   = (const float*)d_in[5];
  const float* m_conv_w = (const float*)d_in[6];
  const float* m_conv_b = (const float*)d_in[7];
  const float* m_xp_w   = (const float*)d_in[8];
  const float* m_dt_w   = (const float*)d_in[9];
  const float* m_dt_b   = (const float*)d_in[10];
  const float* m_A_log  = (const float*)d_in[11];
  const float* m_D      = (const float*)d_in[12];
  const float* m_out_w  = (const float*)d_in[13];
  const float* ffn_ln_g = (const float*)d_in[14];
  const float* ffn_ln_b = (const float*)d_in[15];
  const float* ffn_w1   = (const float*)d_in[16];
  const float* ffn_b1   = (const float*)d_in[17];
  const float* ffn_w2   = (const float*)d_in[18];
  const float* ffn_b2   = (const float*)d_in[19];
  const float* enc_g    = (const float*)d_in[20];
  const float* enc_b    = (const float*)d_in[21];
  const float* proj_w   = (const float*)d_in[22];
  const float* proj_b   = (const float*)d_in[23];
  float* out = (float*)d_out;

  char* ws = (char*)d_ws;
  const size_t MB = 1024 * 1024;
  float* h      = (float*)(ws + 0);        //  8 MB fp32 residual stream
  short* hn     = (short*)(ws + 8 * MB);   //  4 MB LN output bf16
  short* xz     = (short*)(ws + 12 * MB);  // 16 MB [M][2048] per-dir
  short* xc     = (short*)(ws + 28 * MB);  //  8 MB [M][1024] per-dir
  short* xdbl   = (short*)(ws + 36 * MB);  // .5 MB [M][64]
  float* stats  = (float*)(ws + 36 * MB + 512 * 1024);          // 64 KB
  unsigned short* dtb = (unsigned short*)(ws + 37 * MB); // 8 MB fp16 dt; scan_p3 dir1 writes y in place
  unsigned short* part_h = (unsigned short*)(ws + 45 * MB);     // 4 MB (scan only)
  unsigned short* part_A = (unsigned short*)(ws + 49 * MB);     // 4 MB (scan only)
  short* vtmp   = (short*)(ws + 47 * MB);  // 4 MB bf16 mamba out (after scans done)
  short* ftmp   = (short*)(ws + 47 * MB);  // 4 MB bf16 ffn2 out (aliases vtmp, sequential)
  short* yact0  = (short*)(ws + 53 * MB);  //  8 MB y(dir0); xnT aliases pre-layer
  short* xnT    = (short*)(ws + 53 * MB);
  float* means = stats, *stdevp = stats + 4096, *rstd = stats + 8192, *xlast = stats + 12288;

  dim3 blk(256);
  const int NOSPLIT = 1 << 30;

  stats_k<<<dim3(2, B_), blk, 0, stream>>>(x, means, stdevp, rstd, xlast);
  tnorm_k<<<dim3(8, 8, B_), blk, 0, stream>>>(x, means, rstd, xnT);
  // emb: M=4096, N=512, K=512 — 64x64 BK=64, grid (64, 8)
  gemm_k<EPI_F32_BIAS, 64, 64, 64><<<dim3(64, 8), blk, 0, stream>>>(
      xnT, xnT, emb_w, emb_w, NOSPLIT, DM_, L_, L_, L_,
      h, nullptr, DM_, emb_b, nullptr, nullptr, nullptr);

  for (int il = 0; il < EL_; il++) {
    if (il == 0)
      ln_k<0><<<dim3(4096), blk, 0, stream>>>(h, nullptr, nullptr, ln_g, ln_b, hn);
    else
      ln_k<2><<<dim3(4096), blk, 0, stream>>>(h, ftmp, ffn_b2 + (il - 1) * DM_,
          ln_g + il * DM_, ln_b + il * DM_, hn);
    for (int dir = 0; dir < 2; dir++) {
      int mod = 2 * il + dir;
      // in-proj: N=2048, K=512 — 128x128 BK=32, grid (32, 16) = 512 blocks
      gemm_k<EPI_BF16, 128, 128, 32><<<dim3(32, 16), blk, 0, stream>>>(
          hn, hn, m_in_w + (size_t)mod * 2 * DI_ * DM_,
          m_in_w + (size_t)mod * 2 * DI_ * DM_, NOSPLIT, 2 * DI_, DM_, DM_, DM_,
          nullptr, xz, 2 * DI_, nullptr, nullptr, nullptr, nullptr);
      if (dir == 0)
        conv_k<0><<<dim3(16384), blk, 0, stream>>>(
            xz, m_conv_w + (size_t)mod * DI_ * DC_, m_conv_b + (size_t)mod * DI_, xc);
      else
        conv_k<1><<<dim3(16384), blk, 0, stream>>>(
            xz, m_conv_w + (size_t)mod * DI_ * DC_, m_conv_b + (size_t)mod * DI_, xc);
      // xdbl: N=64, K=1024 — 32x64 BK=64, grid (128, 1)
      gemm_k<EPI_BF16, 32, 64, 64><<<dim3(128, 1), blk, 0, stream>>>(
          xc, xc, m_xp_w + (size_t)mod * (DTR_ + 2 * DS_) * DI_,
          m_xp_w + (size_t)mod * (DTR_ + 2 * DS_) * DI_, NOSPLIT,
          DTR_ + 2 * DS_, DI_, DI_, DI_,
          nullptr, xdbl, DTR_ + 2 * DS_, nullptr, nullptr, nullptr, nullptr);
      // dt: N=1024, K=32 — 64x64 BK=32, grid (64, 16)
      gemm_k<EPI_F16_SOFTPLUS, 64, 64, 32><<<dim3(64, 16), blk, 0, stream>>>(
          xdbl, xdbl, m_dt_w + (size_t)mod * DI_ * DTR_,
          m_dt_w + (size_t)mod * DI_ * DTR_, NOSPLIT, DI_, DTR_, DTR_ + 2 * DS_, DTR_,
          nullptr, (short*)dtb, DI_, m_dt_b + (size_t)mod * DI_, nullptr, nullptr, nullptr);
      const float* Alog = m_A_log + (size_t)mod * DI_ * DS_;
      const float* Dp = m_D + (size_t)mod * DI_;
      short* ydst = (dir == 0) ? yact0 : (short*)dtb;   // dir1: in-place over dtb
      if (dir == 0) {
        scan_p1<0><<<dim3(32, CH_), blk, 0, stream>>>(dtb, xc, xdbl, Alog, part_h, part_A);
        scan_p2<<<dim3(512), blk, 0, stream>>>(part_h, part_A);
        scan_p3<0><<<dim3(32, CH_), blk, 0, stream>>>(dtb, xc, xdbl, xz, Alog, Dp, part_h, ydst);
      } else {
        scan_p1<1><<<dim3(32, CH_), blk, 0, stream>>>(dtb, xc, xdbl, Alog, part_h, part_A);
        scan_p2<<<dim3(512), blk, 0, stream>>>(part_h, part_A);
        scan_p3<1><<<dim3(32, CH_), blk, 0, stream>>>(dtb, xc, xdbl, xz, Alog, Dp, part_h, ydst);
      }
    }
    // out-proj (concat-K): vtmp = 0.5*(yf.Wf^T + yb.Wb^T) — K=2048, grid (64,8)
    gemm_k<EPI_HALF_BF16, 64, 64, 64><<<dim3(64, 8), blk, 0, stream>>>(
        yact0, (const short*)dtb,
        m_out_w + (size_t)(2 * il) * DM_ * DI_,
        m_out_w + (size_t)(2 * il + 1) * DM_ * DI_,
        DI_, DM_, 2 * DI_, DI_, DI_,
        nullptr, vtmp, DM_, nullptr, nullptr, nullptr, nullptr);
    // fused: h += vtmp, then LN
    ln_k<1><<<dim3(4096), blk, 0, stream>>>(h, vtmp, nullptr,
        ffn_ln_g + il * DM_, ffn_ln_b + il * DM_, hn);
    // ffn1: N=2048, K=512 — 128x128 BK=32, grid (32, 16)
    gemm_k<EPI_GELU, 128, 128, 32><<<dim3(32, 16), blk, 0, stream>>>(
        hn, hn, ffn_w1 + (size_t)il * 4 * DM_ * DM_,
        ffn_w1 + (size_t)il * 4 * DM_ * DM_, NOSPLIT, 4 * DM_, DM_, DM_, DM_,
        nullptr, xz, 4 * DM_, ffn_b1 + (size_t)il * 4 * DM_, nullptr, nullptr, nullptr);
    // ffn2: N=512, K=2048 — 64x64 BK=64, grid (64, 8); streaming bf16 out
    gemm_k<EPI_BF16, 64, 64, 64><<<dim3(64, 8), blk, 0, stream>>>(
        xz, xz, ffn_w2 + (size_t)il * DM_ * 4 * DM_,
        ffn_w2 + (size_t)il * DM_ * 4 * DM_, NOSPLIT, DM_, 4 * DM_, 4 * DM_, 4 * DM_,
        nullptr, ftmp, DM_, nullptr, nullptr, nullptr, nullptr);
    // h += ftmp + ffn_b2 happens in the next layer's LN (or enc-LN below)
  }

  ln_k<2><<<dim3(4096), blk, 0, stream>>>(h, ftmp, ffn_b2 + 2 * DM_,
      enc_g, enc_b, hn);
  // proj: N=96, K=512 — 64x64 BK=64, grid (64, 2)
  gemm_k<EPI_PROJ, 64, 64, 64><<<dim3(64, 2), blk, 0, stream>>>(
      hn, hn, proj_w, proj_w, NOSPLIT, PL_, DM_, DM_, DM_,
      out, nullptr, 0, proj_b, xlast, stdevp, means);
}